// Round 2
// baseline (359.899 us; speedup 1.0000x reference)
//
#include <hip/hip_runtime.h>

// ---------------------------------------------------------------------------
// PAM: out = gamma * softmax((X Wb)(X Wc)^T) (X Wd) + X
// B=4, N=4096, C=512, CR=64. fp32 in/out; bf16 MFMA with hi/lo Q/K split.
// Materialized-P design: P = exp(S - 90) bf16 (softmax shift-invariance).
// Round 10: qkv_kernel split into 6 column-groups (grid 256x6): {Q},{K},
// {V pairs}. Round 9 ran grid=256 = 1 block/CU = 1 wave/SIMD (Occupancy 11%,
// MfmaUtil 4.8%) -> pure latency starvation on the W-load->MFMA chain.
// 6 groups give ~4 co-resident blocks/CU (16 waves/CU); V-groups drop the
// xl lo-split (-32 VGPR). X re-reads are LLC-served (33.5 MB << 256 MB L3).
// ---------------------------------------------------------------------------

typedef __bf16 bf16_t;
typedef __bf16 bf16x8 __attribute__((ext_vector_type(8)));
typedef float f32x4 __attribute__((ext_vector_type(4)));
typedef unsigned long long u64;

#define NN 4096
#define CC 512
#define VSTRIDE 4160u
#define PSTRIDE 4160u
#define ESHIFT 90.0f

// workspace layout, bf16 elements. P overlaps the W region (dead after qkv).
#define OFF_QH 0u
#define OFF_QL 1048576u
#define OFF_KH 2097152u
#define OFF_KL 3145728u
#define OFF_VT 4194304u            // Vt[b][c][VSTRIDE]
#define OFF_WBH 29491200u
#define OFF_WBL 29523968u
#define OFF_WCH 29556736u
#define OFF_WCL 29589504u
#define OFF_WD  29622272u
#define OFF_P   12713984u          // P[b][n][PSTRIDE] bf16 (136 MB)
#define PBATCH  17039360u          // 4096*4160

static __device__ __forceinline__ f32x4 mfma16(bf16x8 a, bf16x8 b, f32x4 c) {
    return __builtin_amdgcn_mfma_f32_16x16x32_bf16(a, b, c, 0, 0, 0);
}

static __device__ __forceinline__ void load_lds16(const bf16_t* g, bf16_t* l) {
    __builtin_amdgcn_global_load_lds(
        (const __attribute__((address_space(1))) unsigned int*)g,
        (__attribute__((address_space(3))) unsigned int*)l, 16, 0, 0);
}

// ------------------- K0: prep (W transpose + hi/lo, W-only) -----------------
__global__ __launch_bounds__(256) void prep_kernel(const float* __restrict__ Wb,
                                                   const float* __restrict__ Wc,
                                                   const float* __restrict__ Wd,
                                                   bf16_t* __restrict__ ws) {
    int j = blockIdx.x * 256 + threadIdx.x;
    if (j < 32768) {                           // Wb [512][64] -> hi/lo [64][512]
        int n = j >> 9, k = j & 511;
        float v = Wb[k * 64 + n];
        bf16_t h = (bf16_t)v;
        ws[OFF_WBH + j] = h;
        ws[OFF_WBL + j] = (bf16_t)(v - (float)h);
    } else if (j < 65536) {
        int j2 = j - 32768;
        int n = j2 >> 9, k = j2 & 511;
        float v = Wc[k * 64 + n];
        bf16_t h = (bf16_t)v;
        ws[OFF_WCH + j2] = h;
        ws[OFF_WCL + j2] = (bf16_t)(v - (float)h);
    } else if (j < 327680) {                   // Wd [512][512]
        int j2 = j - 65536;
        int n = j2 >> 9, k = j2 & 511;
        ws[OFF_WD + j2] = (bf16_t)Wd[k * 512 + n];
    }
}

// --------------------------- K1: fused QKV projection -----------------------
// grid (256, 6): blockIdx.x = 64-row stripe, blockIdx.y = output group:
//   g=0: Q (hi/lo x, hi/lo W -> 3 MFMA/product)
//   g=1: K (same)
//   g=2..5: V column pairs nT = (g-2)*2 + {0,1} (hi-only x)
// Each lane holds its X row segment in VGPRs (statically indexed).
__global__ __launch_bounds__(256, 1) void qkv_kernel(const float* __restrict__ x,
                                                     bf16_t* __restrict__ ws) {
    int mt = blockIdx.x;                       // 0..255
    int g  = blockIdx.y;                       // 0..5
    int tid = threadIdx.x;
    int w = tid >> 6, lane = tid & 63, quad = lane >> 4, l16 = lane & 15;

    __shared__ __align__(16) bf16_t Vs[64][72];

    const float* xrow = x + (size_t)(mt * 64 + w * 16 + l16) * 512 + quad * 8;

    if (g < 2) {
        // ---- X rows -> register-resident A fragments (hi/lo) ----
        bf16x8 xh[16], xl[16];
#pragma unroll
        for (int ks = 0; ks < 16; ++ks) {
            f32x4 a0 = *(const f32x4*)(xrow + ks * 32);
            f32x4 a1 = *(const f32x4*)(xrow + ks * 32 + 4);
#pragma unroll
            for (int j = 0; j < 4; ++j) {
                bf16_t h0 = (bf16_t)a0[j];
                bf16_t h1 = (bf16_t)a1[j];
                xh[ks][j] = h0;     xl[ks][j] = (bf16_t)(a0[j] - (float)h0);
                xh[ks][4 + j] = h1; xl[ks][4 + j] = (bf16_t)(a1[j] - (float)h1);
            }
        }

        const bf16_t* wh = ws + (g == 0 ? OFF_WBH : OFF_WCH);
        const bf16_t* wl = ws + (g == 0 ? OFF_WBL : OFF_WCL);
        f32x4 acc[4];
#pragma unroll
        for (int nt = 0; nt < 4; ++nt) acc[nt] = (f32x4){0.f, 0.f, 0.f, 0.f};
#pragma unroll
        for (int ks = 0; ks < 16; ++ks) {
#pragma unroll
            for (int nt = 0; nt < 4; ++nt) {
                size_t wo = (size_t)(nt * 16 + l16) * 512 + ks * 32 + quad * 8;
                bf16x8 bh = *(const bf16x8*)(wh + wo);
                bf16x8 bl = *(const bf16x8*)(wl + wo);
                acc[nt] = mfma16(xh[ks], bh, acc[nt]);
                acc[nt] = mfma16(xh[ks], bl, acc[nt]);
                acc[nt] = mfma16(xl[ks], bh, acc[nt]);
            }
        }
        unsigned base_h = (g == 0) ? OFF_QH : OFF_KH;
        unsigned base_l = (g == 0) ? OFF_QL : OFF_KL;
#pragma unroll
        for (int nt = 0; nt < 4; ++nt) {
            int gc = nt * 16 + l16;
#pragma unroll
            for (int r = 0; r < 4; ++r) {
                int gr = mt * 64 + w * 16 + quad * 4 + r;
                int b = gr >> 12, np = gr & 4095;
                float v = acc[nt][r];
                bf16_t h = (bf16_t)v;
                size_t o = ((size_t)(b * 4096 + np)) * 64 + gc;
                ws[base_h + o] = h;
                ws[base_l + o] = (bf16_t)(v - (float)h);
            }
        }
    } else {
        // ---- V groups: hi-only X fragments ----
        bf16x8 xh[16];
#pragma unroll
        for (int ks = 0; ks < 16; ++ks) {
            f32x4 a0 = *(const f32x4*)(xrow + ks * 32);
            f32x4 a1 = *(const f32x4*)(xrow + ks * 32 + 4);
#pragma unroll
            for (int j = 0; j < 4; ++j) {
                xh[ks][j] = (bf16_t)a0[j];
                xh[ks][4 + j] = (bf16_t)a1[j];
            }
        }

        for (int t = 0; t < 2; ++t) {
            int nT = (g - 2) * 2 + t;
            const bf16_t* wp = ws + OFF_WD + (size_t)nT * 64 * 512;
            f32x4 acc[4];
#pragma unroll
            for (int nt = 0; nt < 4; ++nt) acc[nt] = (f32x4){0.f, 0.f, 0.f, 0.f};
#pragma unroll
            for (int ks = 0; ks < 16; ++ks) {
#pragma unroll
                for (int nt = 0; nt < 4; ++nt) {
                    bf16x8 bb = *(const bf16x8*)(wp + (size_t)(nt * 16 + l16) * 512 + ks * 32 + quad * 8);
                    acc[nt] = mfma16(xh[ks], bb, acc[nt]);
                }
            }
            // acc[nt][r] = V[pos = mt*64 + w*16 + quad*4 + r][ch = nT*64 + nt*16 + l16]
#pragma unroll
            for (int nt = 0; nt < 4; ++nt) {
                bf16_t pk[4];
#pragma unroll
                for (int r = 0; r < 4; ++r) pk[r] = (bf16_t)acc[nt][r];
                *(u64*)&Vs[nt * 16 + l16][w * 16 + quad * 4] = *(u64*)pk;
            }
            __syncthreads();
            int gr0 = mt * 64;
            int bb = gr0 >> 12, np0 = gr0 & 4095;
            int ch = tid >> 2, seg = tid & 3;
            f32x4 d0 = *(const f32x4*)&Vs[ch][seg * 16];
            f32x4 d1 = *(const f32x4*)&Vs[ch][seg * 16 + 8];
            bf16_t* dst = ws + OFF_VT +
                ((size_t)bb * 512 + (size_t)(nT * 64 + ch)) * VSTRIDE + np0 + seg * 16;
            *(f32x4*)(dst) = d0;
            *(f32x4*)(dst + 8) = d1;
            __syncthreads();
        }
    }
}

// --------------------------- K2: scores + exp -------------------------------
// Block = (b, nt, mt) 128x128 S-tile; 4 waves in 2x2 (wr,wc), each 64x64.
// P = exp(S - 90) bf16, transposed via LDS, 256B-coalesced stores.
__global__ __launch_bounds__(256, 2) void score_kernel(bf16_t* __restrict__ ws) {
    int idx = blockIdx.x;
    int mt = idx & 31;
    int nt = (idx >> 5) & 31;
    int b  = idx >> 10;
    int tid = threadIdx.x;
    int w = tid >> 6, lane = tid & 63, quad = lane >> 4, l16 = lane & 15;
    int wr = w >> 1, wc = w & 1;

    __shared__ __align__(16) bf16_t Ls[128][136];

    const bf16_t* Qh = ws + OFF_QH + (size_t)b * NN * 64;
    const bf16_t* Ql = ws + OFF_QL + (size_t)b * NN * 64;
    const bf16_t* Kh = ws + OFF_KH + (size_t)b * NN * 64;
    const bf16_t* Kl = ws + OFF_KL + (size_t)b * NN * 64;

    bf16x8 qh[4][2], ql[4][2];
#pragma unroll
    for (int rt = 0; rt < 4; ++rt) {
        size_t qo = (size_t)(nt * 128 + wr * 64 + rt * 16 + l16) * 64 + quad * 8;
        qh[rt][0] = *(const bf16x8*)(Qh + qo);
        qh[rt][1] = *(const bf16x8*)(Qh + qo + 32);
        ql[rt][0] = *(const bf16x8*)(Ql + qo);
        ql[rt][1] = *(const bf16x8*)(Ql + qo + 32);
    }

    f32x4 s[4][4];
#pragma unroll
    for (int ct = 0; ct < 4; ++ct) {
        size_t ko = (size_t)(mt * 128 + wc * 64 + ct * 16 + l16) * 64 + quad * 8;
        bf16x8 kh0 = *(const bf16x8*)(Kh + ko);
        bf16x8 kh1 = *(const bf16x8*)(Kh + ko + 32);
        bf16x8 kl0 = *(const bf16x8*)(Kl + ko);
        bf16x8 kl1 = *(const bf16x8*)(Kl + ko + 32);
#pragma unroll
        for (int rt = 0; rt < 4; ++rt) {
            f32x4 a = (f32x4){0.f, 0.f, 0.f, 0.f};
            a = mfma16(qh[rt][0], kh0, a);
            a = mfma16(qh[rt][1], kh1, a);
            a = mfma16(qh[rt][0], kl0, a);
            a = mfma16(qh[rt][1], kl1, a);
            a = mfma16(ql[rt][0], kh0, a);
            a = mfma16(ql[rt][1], kh1, a);
            s[rt][ct] = a;
        }
    }

#pragma unroll
    for (int rt = 0; rt < 4; ++rt)
#pragma unroll
        for (int ct = 0; ct < 4; ++ct)
#pragma unroll
            for (int r = 0; r < 4; ++r) {
                float p = __expf(s[rt][ct][r] - ESHIFT);
                Ls[wr * 64 + rt * 16 + quad * 4 + r][wc * 64 + ct * 16 + l16] = (bf16_t)p;
            }
    __syncthreads();

    bf16_t* P = ws + OFF_P + (size_t)b * PBATCH;
    int row0 = tid >> 4, chunk = tid & 15;
#pragma unroll
    for (int it = 0; it < 8; ++it) {
        int row = it * 16 + row0;
        f32x4 d = *(const f32x4*)&Ls[row][chunk * 8];
        *(f32x4*)(P + (size_t)(nt * 128 + row) * PSTRIDE + mt * 128 + chunk * 8) = d;
    }
}

// --------------------------- K3: O = P V + epilogue -------------------------
// Block = (b, nt, ct4): 128 rows x 128 cols output, K=4096 in 64 steps of 64.
// Double-buffered LDS tiles Pt/Vt [128 rows][64 m] with XOR chunk-swizzle:
// LDS 16B-chunk index = (m_chunk ^ (row & 7)). global_load_lds writes linearly
// (dest = tid*16B); the swizzle is realized by pre-swizzling the GLOBAL source
// chunk per staging thread; ds_read applies the same XOR. One barrier per
// K-step; next tile's loads are issued BEFORE compute so LLC latency hides
// under MFMA.
__global__ __launch_bounds__(256, 2) void pv_kernel(const float* __restrict__ x,
                                                    const float* __restrict__ gamma_p,
                                                    const bf16_t* __restrict__ ws,
                                                    float* __restrict__ out) {
    int idx = blockIdx.x;
    int ct4 = idx & 3;
    int b   = (idx >> 2) & 3;
    int nt  = idx >> 4;
    int tid = threadIdx.x;
    int w = tid >> 6, lane = tid & 63, quad = lane >> 4, l16 = lane & 15;
    int wr = w >> 1, wc = w & 1;

    __shared__ __align__(16) bf16_t Pt[2][8192];   // [128 rows][64 m] swizzled
    __shared__ __align__(16) bf16_t Vt[2][8192];   // [128 ch][64 m] swizzled

    const bf16_t* P = ws + OFF_P + (size_t)b * PBATCH + (size_t)(nt * 128) * PSTRIDE;
    const bf16_t* V = ws + OFF_VT + (size_t)b * CC * VSTRIDE + (size_t)(ct4 * 128) * VSTRIDE;

    // Staging: thread tid fills LDS bytes [tid*16, tid*16+16) of each 4KB
    // segment i (rows i*32..i*32+31). Linear dest row = i*32 + (tid>>3),
    // dest chunk = tid&7; source chunk = (tid&7) ^ (row&7).
    int sr = tid >> 3;                         // 0..31
    int sc = (tid & 7) ^ (sr & 7);             // pre-swizzled source chunk
    const bf16_t* gp = P + (size_t)sr * PSTRIDE + sc * 8;
    const bf16_t* gv = V + (size_t)sr * VSTRIDE + sc * 8;

    f32x4 o[4][4];
#pragma unroll
    for (int rt = 0; rt < 4; ++rt)
#pragma unroll
        for (int ct = 0; ct < 4; ++ct) o[rt][ct] = (f32x4){0.f, 0.f, 0.f, 0.f};
    f32x4 osum[4];
#pragma unroll
    for (int rt = 0; rt < 4; ++rt) osum[rt] = (f32x4){0.f, 0.f, 0.f, 0.f};

    bf16_t onev = (bf16_t)1.0f;
    bf16x8 vones = {onev, onev, onev, onev, onev, onev, onev, onev};

    auto stage = [&](int buf, int t) {
        int m0 = t * 64;
        load_lds16(gp + m0,                  &Pt[buf][tid * 8]);
        load_lds16(gp + 32u * PSTRIDE + m0,  &Pt[buf][2048 + tid * 8]);
        load_lds16(gp + 64u * PSTRIDE + m0,  &Pt[buf][4096 + tid * 8]);
        load_lds16(gp + 96u * PSTRIDE + m0,  &Pt[buf][6144 + tid * 8]);
        load_lds16(gv + m0,                  &Vt[buf][tid * 8]);
        load_lds16(gv + 32u * VSTRIDE + m0,  &Vt[buf][2048 + tid * 8]);
        load_lds16(gv + 64u * VSTRIDE + m0,  &Vt[buf][4096 + tid * 8]);
        load_lds16(gv + 96u * VSTRIDE + m0,  &Vt[buf][6144 + tid * 8]);
    };

    auto compute = [&](int buf) {
#pragma unroll
        for (int kk = 0; kk < 2; ++kk) {
            bf16x8 pa[4], vb[4];
#pragma unroll
            for (int rt = 0; rt < 4; ++rt) {
                int R = wr * 64 + rt * 16 + l16;
                int mc = (kk * 4 + quad) ^ (R & 7);
                pa[rt] = *(const bf16x8*)&Pt[buf][R * 64 + mc * 8];
            }
#pragma unroll
            for (int ct = 0; ct < 4; ++ct) {
                int Rv = wc * 64 + ct * 16 + l16;
                int mc = (kk * 4 + quad) ^ (Rv & 7);
                vb[ct] = *(const bf16x8*)&Vt[buf][Rv * 64 + mc * 8];
            }
#pragma unroll
            for (int ct = 0; ct < 4; ++ct)
#pragma unroll
                for (int rt = 0; rt < 4; ++rt)
                    o[rt][ct] = mfma16(pa[rt], vb[ct], o[rt][ct]);
            if (wc == 0) {
#pragma unroll
                for (int rt = 0; rt < 4; ++rt)
                    osum[rt] = mfma16(pa[rt], vones, osum[rt]);
            }
        }
    };

    stage(0, 0);
    __syncthreads();                            // drains staging vmcnt
    for (int t = 0; t < 63; ++t) {
        int cur = t & 1;
        stage(cur ^ 1, t + 1);                  // issue next tile BEFORE compute
        compute(cur);
        __syncthreads();                        // drains next-tile staging too
    }
    compute(1);                                 // tile 63 (buf 1), no prefetch

    // rsum via LDS: Pt[0] is dead (last read at t=62, barrier after) -> alias.
    float* rsum_s = (float*)&Pt[0][0];
    if (wc == 0 && l16 == 0) {
#pragma unroll
        for (int rt = 0; rt < 4; ++rt)
#pragma unroll
            for (int r = 0; r < 4; ++r)
                rsum_s[wr * 64 + rt * 16 + quad * 4 + r] = osum[rt][r];
    }
    __syncthreads();

    float g = gamma_p[0];
#pragma unroll
    for (int rt = 0; rt < 4; ++rt) {
        f32x4 rs = *(const f32x4*)&rsum_s[wr * 64 + rt * 16 + quad * 4];
        f32x4 linv;
#pragma unroll
        for (int r = 0; r < 4; ++r) linv[r] = 1.0f / rs[r];
#pragma unroll
        for (int ct = 0; ct < 4; ++ct) {
#pragma unroll
            for (int r = 0; r < 4; ++r) {
                int n = nt * 128 + wr * 64 + rt * 16 + quad * 4 + r;
                int c = ct4 * 128 + wc * 64 + ct * 16 + l16;
                size_t off = ((size_t)(b * 4096 + n)) * 512 + c;
                out[off] = g * (o[rt][ct][r] * linv[r]) + x[off];
            }
        }
    }
}

// ---------------------------------------------------------------------------
extern "C" void kernel_launch(void* const* d_in, const int* in_sizes, int n_in,
                              void* d_out, int out_size, void* d_ws, size_t ws_size,
                              hipStream_t stream) {
    const float* x     = (const float*)d_in[0];
    const float* Wb    = (const float*)d_in[1];
    const float* Wc    = (const float*)d_in[2];
    const float* Wd    = (const float*)d_in[3];
    const float* gamma = (const float*)d_in[4];
    bf16_t* ws = (bf16_t*)d_ws;
    float* out = (float*)d_out;

    prep_kernel<<<1280, 256, 0, stream>>>(Wb, Wc, Wd, ws);
    qkv_kernel<<<dim3(256, 6), 256, 0, stream>>>(x, ws);
    score_kernel<<<4096, 256, 0, stream>>>(ws);
    pv_kernel<<<512, 256, 0, stream>>>(x, gamma, ws, out);
}

// Round 3
// 307.238 us; speedup vs baseline: 1.1714x; 1.1714x over previous
//
#include <hip/hip_runtime.h>

// ---------------------------------------------------------------------------
// PAM: out = gamma * softmax((X Wb)(X Wc)^T) (X Wd) + X
// B=4, N=4096, C=512, CR=64. fp32 in/out; bf16 MFMA with hi/lo Q/K split.
// Materialized-P design: P = exp(S - 90) bf16 (softmax shift-invariance).
// Round 11: qkv inputs pre-permuted to MFMA fragment-major order.
// R10 diagnosis: qkv was line-traffic-bound (every 16B fragment load strided
// by 1KB -> 64 lines/wave-load, 4x amplification, ~3.9GB L2 lines ~= 110us).
// Now: prep writes W (hi/lo) in B-frag order; new xprep writes Xh/Xl bf16 in
// A-frag order (one-time hi/lo, coalesced). Every qkv load = base + lane*16B.
// ---------------------------------------------------------------------------

typedef __bf16 bf16_t;
typedef __bf16 bf16x8 __attribute__((ext_vector_type(8)));
typedef float f32x4 __attribute__((ext_vector_type(4)));
typedef unsigned long long u64;

#define NN 4096
#define CC 512
#define VSTRIDE 4160u
#define PSTRIDE 4160u
#define ESHIFT 90.0f

// workspace layout, bf16 elements. P overlaps the W and Xfrag regions
// (both dead after qkv).
#define OFF_QH 0u
#define OFF_QL 1048576u
#define OFF_KH 2097152u
#define OFF_KL 3145728u
#define OFF_VT 4194304u            // Vt[b][c][VSTRIDE]
#define OFF_WBH 29491200u          // Wb hi, frag-major [4][16][64][8]
#define OFF_WBL 29523968u
#define OFF_WCH 29556736u
#define OFF_WCL 29589504u
#define OFF_WD  29622272u          // Wd, frag-major [8][4][16][64][8]
#define OFF_XHF 46137344u          // X hi, frag-major [256][4][16][64][8]
#define OFF_XLF 54525952u          // X lo
#define OFF_P   12713984u          // P[b][n][PSTRIDE] bf16 (136 MB)
#define PBATCH  17039360u          // 4096*4160

static __device__ __forceinline__ f32x4 mfma16(bf16x8 a, bf16x8 b, f32x4 c) {
    return __builtin_amdgcn_mfma_f32_16x16x32_bf16(a, b, c, 0, 0, 0);
}

static __device__ __forceinline__ void load_lds16(const bf16_t* g, bf16_t* l) {
    __builtin_amdgcn_global_load_lds(
        (const __attribute__((address_space(1))) unsigned int*)g,
        (__attribute__((address_space(3))) unsigned int*)l, 16, 0, 0);
}

// ------------------- K0: prep (W -> fragment-major hi/lo) -------------------
// One thread per 16B fragment chunk. Chunk (nt, ks, lane=(quad,l16)) holds
// W[k = ks*32 + quad*8 + i][col = nt*16 + l16], i=0..7 — exactly the bf16x8
// the qkv MFMA B-operand needs. Writes coalesced; reads strided (tiny kernel).
__global__ __launch_bounds__(256) void prep_kernel(const float* __restrict__ Wb,
                                                   const float* __restrict__ Wc,
                                                   const float* __restrict__ Wd,
                                                   bf16_t* __restrict__ ws) {
    int j = blockIdx.x * 256 + threadIdx.x;
    if (j < 8192) {                            // Wb / Wc hi+lo frags
        const float* W = (j < 4096) ? Wb : Wc;
        unsigned oh = (j < 4096) ? OFF_WBH : OFF_WCH;
        unsigned ol = (j < 4096) ? OFF_WBL : OFF_WCL;
        int jc = j & 4095;
        int nt = jc >> 10, ks = (jc >> 6) & 15, lane = jc & 63;
        int quad = lane >> 4, l16 = lane & 15;
        int col = nt * 16 + l16, k0 = ks * 32 + quad * 8;
        bf16x8 h, l;
#pragma unroll
        for (int i = 0; i < 8; ++i) {
            float v = W[(k0 + i) * 64 + col];
            bf16_t hv = (bf16_t)v;
            h[i] = hv;
            l[i] = (bf16_t)(v - (float)hv);
        }
        *(bf16x8*)(ws + oh + (size_t)jc * 8) = h;
        *(bf16x8*)(ws + ol + (size_t)jc * 8) = l;
    } else if (j < 40960) {                    // Wd frags (hi only)
        int jc = j - 8192;
        int nT = jc >> 12, nt = (jc >> 10) & 3, ks = (jc >> 6) & 15, lane = jc & 63;
        int quad = lane >> 4, l16 = lane & 15;
        int col = nT * 64 + nt * 16 + l16, k0 = ks * 32 + quad * 8;
        bf16x8 h;
#pragma unroll
        for (int i = 0; i < 8; ++i)
            h[i] = (bf16_t)Wd[(k0 + i) * 512 + col];
        *(bf16x8*)(ws + OFF_WD + (size_t)jc * 8) = h;
    }
}

// ------------------- K0b: xprep (X -> fragment-major hi/lo bf16) ------------
// Block = one 64-row stripe. Reads coalesced (32B/thread), writes the 16B
// fragment chunks (scattered within a 64KB window; L2 write-combines, HBM
// writeback is full lines since the permutation is dense per stripe).
__global__ __launch_bounds__(256) void xprep_kernel(const float* __restrict__ x,
                                                    bf16_t* __restrict__ ws) {
    int mt = blockIdx.x;
    int tid = threadIdx.x;
    const float* xb = x + (size_t)mt * 32768;
#pragma unroll
    for (int it = 0; it < 16; ++it) {
        int c = it * 256 + tid;                // 16B-pair chunk: 8 f32
        int row = c >> 6, col8 = c & 63;
        f32x4 a0 = *(const f32x4*)(xb + c * 8);
        f32x4 a1 = *(const f32x4*)(xb + c * 8 + 4);
        bf16x8 h, l;
#pragma unroll
        for (int jj = 0; jj < 4; ++jj) {
            bf16_t h0 = (bf16_t)a0[jj];
            bf16_t h1 = (bf16_t)a1[jj];
            h[jj] = h0;     l[jj] = (bf16_t)(a0[jj] - (float)h0);
            h[4 + jj] = h1; l[4 + jj] = (bf16_t)(a1[jj] - (float)h1);
        }
        int w = row >> 4, l16 = row & 15, ks = col8 >> 2, quad = col8 & 3;
        size_t dst = (size_t)mt * 32768 + w * 8192 + ks * 512 + (quad * 16 + l16) * 8;
        *(bf16x8*)(ws + OFF_XHF + dst) = h;
        *(bf16x8*)(ws + OFF_XLF + dst) = l;
    }
}

// --------------------------- K1: fused QKV projection -----------------------
// grid (256, 6): blockIdx.x = 64-row stripe, blockIdx.y = output group:
//   g=0: Q (hi/lo x, hi/lo W -> 3 MFMA/product); g=1: K (same)
//   g=2..5: V column pairs nT = (g-2)*2 + {0,1} (hi-only x)
// All operand loads are fragment-major: base + lane*16B, fully coalesced.
__global__ __launch_bounds__(256, 1) void qkv_kernel(bf16_t* __restrict__ ws) {
    int mt = blockIdx.x;                       // 0..255
    int g  = blockIdx.y;                       // 0..5
    int tid = threadIdx.x;
    int w = tid >> 6, lane = tid & 63, quad = lane >> 4, l16 = lane & 15;

    __shared__ __align__(16) bf16_t Vs[64][72];

    size_t xoff = (size_t)mt * 32768 + w * 8192 + lane * 8;

    if (g < 2) {
        bf16x8 xh[16], xl[16];
#pragma unroll
        for (int ks = 0; ks < 16; ++ks)
            xh[ks] = *(const bf16x8*)(ws + OFF_XHF + xoff + ks * 512);
#pragma unroll
        for (int ks = 0; ks < 16; ++ks)
            xl[ks] = *(const bf16x8*)(ws + OFF_XLF + xoff + ks * 512);

        const bf16_t* whf = ws + (g == 0 ? OFF_WBH : OFF_WCH) + lane * 8;
        const bf16_t* wlf = ws + (g == 0 ? OFF_WBL : OFF_WCL) + lane * 8;
        f32x4 acc[4];
#pragma unroll
        for (int nt = 0; nt < 4; ++nt) acc[nt] = (f32x4){0.f, 0.f, 0.f, 0.f};
#pragma unroll
        for (int ks = 0; ks < 16; ++ks) {
#pragma unroll
            for (int nt = 0; nt < 4; ++nt) {
                bf16x8 bh = *(const bf16x8*)(whf + (nt * 16 + ks) * 512);
                bf16x8 bl = *(const bf16x8*)(wlf + (nt * 16 + ks) * 512);
                acc[nt] = mfma16(xh[ks], bh, acc[nt]);
                acc[nt] = mfma16(xh[ks], bl, acc[nt]);
                acc[nt] = mfma16(xl[ks], bh, acc[nt]);
            }
        }
        unsigned base_h = (g == 0) ? OFF_QH : OFF_KH;
        unsigned base_l = (g == 0) ? OFF_QL : OFF_KL;
#pragma unroll
        for (int nt = 0; nt < 4; ++nt) {
            int gc = nt * 16 + l16;
#pragma unroll
            for (int r = 0; r < 4; ++r) {
                int gr = mt * 64 + w * 16 + quad * 4 + r;
                int b = gr >> 12, np = gr & 4095;
                float v = acc[nt][r];
                bf16_t h = (bf16_t)v;
                size_t o = ((size_t)(b * 4096 + np)) * 64 + gc;
                ws[base_h + o] = h;
                ws[base_l + o] = (bf16_t)(v - (float)h);
            }
        }
    } else {
        bf16x8 xh[16];
#pragma unroll
        for (int ks = 0; ks < 16; ++ks)
            xh[ks] = *(const bf16x8*)(ws + OFF_XHF + xoff + ks * 512);

        for (int t = 0; t < 2; ++t) {
            int nT = (g - 2) * 2 + t;
            const bf16_t* wdf = ws + OFF_WD + lane * 8;
            f32x4 acc[4];
#pragma unroll
            for (int nt = 0; nt < 4; ++nt) acc[nt] = (f32x4){0.f, 0.f, 0.f, 0.f};
#pragma unroll
            for (int ks = 0; ks < 16; ++ks) {
#pragma unroll
                for (int nt = 0; nt < 4; ++nt) {
                    bf16x8 bb = *(const bf16x8*)(wdf + (size_t)(((nT * 4 + nt) * 16 + ks)) * 512);
                    acc[nt] = mfma16(xh[ks], bb, acc[nt]);
                }
            }
            // acc[nt][r] = V[pos = mt*64 + w*16 + quad*4 + r][ch = nT*64 + nt*16 + l16]
#pragma unroll
            for (int nt = 0; nt < 4; ++nt) {
                bf16_t pk[4];
#pragma unroll
                for (int r = 0; r < 4; ++r) pk[r] = (bf16_t)acc[nt][r];
                *(u64*)&Vs[nt * 16 + l16][w * 16 + quad * 4] = *(u64*)pk;
            }
            __syncthreads();
            int gr0 = mt * 64;
            int bb = gr0 >> 12, np0 = gr0 & 4095;
            int ch = tid >> 2, seg = tid & 3;
            f32x4 d0 = *(const f32x4*)&Vs[ch][seg * 16];
            f32x4 d1 = *(const f32x4*)&Vs[ch][seg * 16 + 8];
            bf16_t* dst = ws + OFF_VT +
                ((size_t)bb * 512 + (size_t)(nT * 64 + ch)) * VSTRIDE + np0 + seg * 16;
            *(f32x4*)(dst) = d0;
            *(f32x4*)(dst + 8) = d1;
            __syncthreads();
        }
    }
}

// --------------------------- K2: scores + exp -------------------------------
// Block = (b, nt, mt) 128x128 S-tile; 4 waves in 2x2 (wr,wc), each 64x64.
// P = exp(S - 90) bf16, transposed via LDS, 256B-coalesced stores.
__global__ __launch_bounds__(256, 2) void score_kernel(bf16_t* __restrict__ ws) {
    int idx = blockIdx.x;
    int mt = idx & 31;
    int nt = (idx >> 5) & 31;
    int b  = idx >> 10;
    int tid = threadIdx.x;
    int w = tid >> 6, lane = tid & 63, quad = lane >> 4, l16 = lane & 15;
    int wr = w >> 1, wc = w & 1;

    __shared__ __align__(16) bf16_t Ls[128][136];

    const bf16_t* Qh = ws + OFF_QH + (size_t)b * NN * 64;
    const bf16_t* Ql = ws + OFF_QL + (size_t)b * NN * 64;
    const bf16_t* Kh = ws + OFF_KH + (size_t)b * NN * 64;
    const bf16_t* Kl = ws + OFF_KL + (size_t)b * NN * 64;

    bf16x8 qh[4][2], ql[4][2];
#pragma unroll
    for (int rt = 0; rt < 4; ++rt) {
        size_t qo = (size_t)(nt * 128 + wr * 64 + rt * 16 + l16) * 64 + quad * 8;
        qh[rt][0] = *(const bf16x8*)(Qh + qo);
        qh[rt][1] = *(const bf16x8*)(Qh + qo + 32);
        ql[rt][0] = *(const bf16x8*)(Ql + qo);
        ql[rt][1] = *(const bf16x8*)(Ql + qo + 32);
    }

    f32x4 s[4][4];
#pragma unroll
    for (int ct = 0; ct < 4; ++ct) {
        size_t ko = (size_t)(mt * 128 + wc * 64 + ct * 16 + l16) * 64 + quad * 8;
        bf16x8 kh0 = *(const bf16x8*)(Kh + ko);
        bf16x8 kh1 = *(const bf16x8*)(Kh + ko + 32);
        bf16x8 kl0 = *(const bf16x8*)(Kl + ko);
        bf16x8 kl1 = *(const bf16x8*)(Kl + ko + 32);
#pragma unroll
        for (int rt = 0; rt < 4; ++rt) {
            f32x4 a = (f32x4){0.f, 0.f, 0.f, 0.f};
            a = mfma16(qh[rt][0], kh0, a);
            a = mfma16(qh[rt][1], kh1, a);
            a = mfma16(qh[rt][0], kl0, a);
            a = mfma16(qh[rt][1], kl1, a);
            a = mfma16(ql[rt][0], kh0, a);
            a = mfma16(ql[rt][1], kh1, a);
            s[rt][ct] = a;
        }
    }

#pragma unroll
    for (int rt = 0; rt < 4; ++rt)
#pragma unroll
        for (int ct = 0; ct < 4; ++ct)
#pragma unroll
            for (int r = 0; r < 4; ++r) {
                float p = __expf(s[rt][ct][r] - ESHIFT);
                Ls[wr * 64 + rt * 16 + quad * 4 + r][wc * 64 + ct * 16 + l16] = (bf16_t)p;
            }
    __syncthreads();

    bf16_t* P = ws + OFF_P + (size_t)b * PBATCH;
    int row0 = tid >> 4, chunk = tid & 15;
#pragma unroll
    for (int it = 0; it < 8; ++it) {
        int row = it * 16 + row0;
        f32x4 d = *(const f32x4*)&Ls[row][chunk * 8];
        *(f32x4*)(P + (size_t)(nt * 128 + row) * PSTRIDE + mt * 128 + chunk * 8) = d;
    }
}

// --------------------------- K3: O = P V + epilogue -------------------------
// Block = (b, nt, ct4): 128 rows x 128 cols output, K=4096 in 64 steps of 64.
// Double-buffered LDS tiles Pt/Vt [128 rows][64 m] with XOR chunk-swizzle:
// linear global_load_lds dest + pre-swizzled global source + swizzled ds_read.
// One barrier per K-step; next tile's loads issued BEFORE compute.
__global__ __launch_bounds__(256, 2) void pv_kernel(const float* __restrict__ x,
                                                    const float* __restrict__ gamma_p,
                                                    const bf16_t* __restrict__ ws,
                                                    float* __restrict__ out) {
    int idx = blockIdx.x;
    int ct4 = idx & 3;
    int b   = (idx >> 2) & 3;
    int nt  = idx >> 4;
    int tid = threadIdx.x;
    int w = tid >> 6, lane = tid & 63, quad = lane >> 4, l16 = lane & 15;
    int wr = w >> 1, wc = w & 1;

    __shared__ __align__(16) bf16_t Pt[2][8192];   // [128 rows][64 m] swizzled
    __shared__ __align__(16) bf16_t Vt[2][8192];   // [128 ch][64 m] swizzled

    const bf16_t* P = ws + OFF_P + (size_t)b * PBATCH + (size_t)(nt * 128) * PSTRIDE;
    const bf16_t* V = ws + OFF_VT + (size_t)b * CC * VSTRIDE + (size_t)(ct4 * 128) * VSTRIDE;

    int sr = tid >> 3;                         // 0..31
    int sc = (tid & 7) ^ (sr & 7);             // pre-swizzled source chunk
    const bf16_t* gp = P + (size_t)sr * PSTRIDE + sc * 8;
    const bf16_t* gv = V + (size_t)sr * VSTRIDE + sc * 8;

    f32x4 o[4][4];
#pragma unroll
    for (int rt = 0; rt < 4; ++rt)
#pragma unroll
        for (int ct = 0; ct < 4; ++ct) o[rt][ct] = (f32x4){0.f, 0.f, 0.f, 0.f};
    f32x4 osum[4];
#pragma unroll
    for (int rt = 0; rt < 4; ++rt) osum[rt] = (f32x4){0.f, 0.f, 0.f, 0.f};

    bf16_t onev = (bf16_t)1.0f;
    bf16x8 vones = {onev, onev, onev, onev, onev, onev, onev, onev};

    auto stage = [&](int buf, int t) {
        int m0 = t * 64;
        load_lds16(gp + m0,                  &Pt[buf][tid * 8]);
        load_lds16(gp + 32u * PSTRIDE + m0,  &Pt[buf][2048 + tid * 8]);
        load_lds16(gp + 64u * PSTRIDE + m0,  &Pt[buf][4096 + tid * 8]);
        load_lds16(gp + 96u * PSTRIDE + m0,  &Pt[buf][6144 + tid * 8]);
        load_lds16(gv + m0,                  &Vt[buf][tid * 8]);
        load_lds16(gv + 32u * VSTRIDE + m0,  &Vt[buf][2048 + tid * 8]);
        load_lds16(gv + 64u * VSTRIDE + m0,  &Vt[buf][4096 + tid * 8]);
        load_lds16(gv + 96u * VSTRIDE + m0,  &Vt[buf][6144 + tid * 8]);
    };

    auto compute = [&](int buf) {
#pragma unroll
        for (int kk = 0; kk < 2; ++kk) {
            bf16x8 pa[4], vb[4];
#pragma unroll
            for (int rt = 0; rt < 4; ++rt) {
                int R = wr * 64 + rt * 16 + l16;
                int mc = (kk * 4 + quad) ^ (R & 7);
                pa[rt] = *(const bf16x8*)&Pt[buf][R * 64 + mc * 8];
            }
#pragma unroll
            for (int ct = 0; ct < 4; ++ct) {
                int Rv = wc * 64 + ct * 16 + l16;
                int mc = (kk * 4 + quad) ^ (Rv & 7);
                vb[ct] = *(const bf16x8*)&Vt[buf][Rv * 64 + mc * 8];
            }
#pragma unroll
            for (int ct = 0; ct < 4; ++ct)
#pragma unroll
                for (int rt = 0; rt < 4; ++rt)
                    o[rt][ct] = mfma16(pa[rt], vb[ct], o[rt][ct]);
            if (wc == 0) {
#pragma unroll
                for (int rt = 0; rt < 4; ++rt)
                    osum[rt] = mfma16(pa[rt], vones, osum[rt]);
            }
        }
    };

    stage(0, 0);
    __syncthreads();
    for (int t = 0; t < 63; ++t) {
        int cur = t & 1;
        stage(cur ^ 1, t + 1);
        compute(cur);
        __syncthreads();
    }
    compute(1);

    float* rsum_s = (float*)&Pt[0][0];
    if (wc == 0 && l16 == 0) {
#pragma unroll
        for (int rt = 0; rt < 4; ++rt)
#pragma unroll
            for (int r = 0; r < 4; ++r)
                rsum_s[wr * 64 + rt * 16 + quad * 4 + r] = osum[rt][r];
    }
    __syncthreads();

    float g = gamma_p[0];
#pragma unroll
    for (int rt = 0; rt < 4; ++rt) {
        f32x4 rs = *(const f32x4*)&rsum_s[wr * 64 + rt * 16 + quad * 4];
        f32x4 linv;
#pragma unroll
        for (int r = 0; r < 4; ++r) linv[r] = 1.0f / rs[r];
#pragma unroll
        for (int ct = 0; ct < 4; ++ct) {
#pragma unroll
            for (int r = 0; r < 4; ++r) {
                int n = nt * 128 + wr * 64 + rt * 16 + quad * 4 + r;
                int c = ct4 * 128 + wc * 64 + ct * 16 + l16;
                size_t off = ((size_t)(b * 4096 + n)) * 512 + c;
                out[off] = g * (o[rt][ct][r] * linv[r]) + x[off];
            }
        }
    }
}

// ---------------------------------------------------------------------------
extern "C" void kernel_launch(void* const* d_in, const int* in_sizes, int n_in,
                              void* d_out, int out_size, void* d_ws, size_t ws_size,
                              hipStream_t stream) {
    const float* x     = (const float*)d_in[0];
    const float* Wb    = (const float*)d_in[1];
    const float* Wc    = (const float*)d_in[2];
    const float* Wd    = (const float*)d_in[3];
    const float* gamma = (const float*)d_in[4];
    bf16_t* ws = (bf16_t*)d_ws;
    float* out = (float*)d_out;

    prep_kernel<<<160, 256, 0, stream>>>(Wb, Wc, Wd, ws);
    xprep_kernel<<<256, 256, 0, stream>>>(x, ws);
    qkv_kernel<<<dim3(256, 6), 256, 0, stream>>>(ws);
    score_kernel<<<4096, 256, 0, stream>>>(ws);
    pv_kernel<<<512, 256, 0, stream>>>(x, gamma, ws, out);
}